// Round 11
// baseline (462.166 us; speedup 1.0000x reference)
//
#include <hip/hip_runtime.h>
#include <hip/hip_bf16.h>
#include <cstdint>
#include <cstddef>

// Problem constants (match reference)
#define BB 2
#define LL 2048
#define DM 1024
#define DI 2048
#define DS 16
#define MM (BB*LL)       // 4096 rows
#define NCAT 2176        // 2048 (W_dt) + 32 (W_x) + 96 pad -> 17 tiles of 128
#define NC 32            // scan chunks (parallel-scan over L)
#define LC (LL/NC)       // 64 timesteps per chunk

typedef __attribute__((ext_vector_type(8))) short short8;   // 8 x bf16 fragment
typedef __attribute__((ext_vector_type(4))) float f32x4;    // MFMA accumulator

__device__ __forceinline__ unsigned short f2bf(float f) {
  union { float f; unsigned int u; } x; x.f = f;
  unsigned int u = x.u;
  unsigned int r = (u + 0x7FFFu + ((u >> 16) & 1u)) >> 16;  // RNE
  return (unsigned short)r;
}

// ---------------- cast fp32 -> bf16 (vectorized) ----------------
__global__ __launch_bounds__(256) void cast_bf16_k(const float* __restrict__ in,
                                                   unsigned short* __restrict__ out, int n) {
  int i = (blockIdx.x * 256 + threadIdx.x) * 4;
  if (i < n) {
    float4 v = *(const float4*)&in[i];
    ushort4 o;
    o.x = f2bf(v.x); o.y = f2bf(v.y); o.z = f2bf(v.z); o.w = f2bf(v.w);
    *(ushort4*)&out[i] = o;
  }
}

// ---------------- transpose + cast: W (RxC f32) -> WT (CxR bf16) ----------------
__global__ __launch_bounds__(256) void transpose_cast_k(const float* __restrict__ W,
                                                        unsigned short* __restrict__ WT,
                                                        int R, int C) {
  __shared__ float tile[32][33];
  int c0 = blockIdx.x * 32;
  int r0 = blockIdx.y * 32;
  int tx = threadIdx.x;        // 0..31
  int ty = threadIdx.y;        // 0..7
#pragma unroll
  for (int i = 0; i < 4; ++i) {
    int r = r0 + ty + i * 8;
    tile[ty + i * 8][tx] = W[(size_t)r * C + c0 + tx];
  }
  __syncthreads();
#pragma unroll
  for (int i = 0; i < 4; ++i) {
    int c = c0 + ty + i * 8;
    WT[(size_t)c * R + r0 + tx] = f2bf(tile[tx][ty + i * 8]);
  }
}

// ---------------- bf16 MFMA GEMM, C = A * Bt^T ----------------
// 3-buffer LDS rotation, counted s_waitcnt vmcnt(4) (T4): iter k stages
// buf[(k+1)%3] and waits only for buf[k%3]'s loads (issued one full iteration
// earlier, oldest-first vmcnt semantics) -- this iteration's stage stays in
// flight across the barrier. NB=3 guarantees the overwritten buffer's last
// reader was iter k-2, already drained by barrier_{k-1}.
#define BM 128
#define BN 128
#define BK 32
template <int MODE>
__global__ __launch_bounds__(256) void gemm_bt_k(const unsigned short* __restrict__ A,
                                                 const unsigned short* __restrict__ Bt,
                                                 float* __restrict__ C,
                                                 int M, int N, int K,
                                                 const float* __restrict__ bias,
                                                 float* __restrict__ C2, int nSplit) {
  __shared__ unsigned short As[3][BM * BK];   // 3 x 8 KB
  __shared__ unsigned short Bs[3][BN * BK];   // 3 x 8 KB
  const int tid  = threadIdx.x;
  const int lane = tid & 63;
  const int wv   = tid >> 6;               // wave 0..3
  const int nTilesN = N / BN;
  const int bm = (blockIdx.x / nTilesN) * BM;
  const int bn = (blockIdx.x % nTilesN) * BN;
  const int wr = wv >> 1, wc = wv & 1;     // 2x2 wave grid, each wave 64x64

  // per-thread staging geometry (wave-uniform LDS dest + lane*16B)
  const int chunk0 = wv;                   // chunks wv and wv+4
  const int eidx0  = chunk0 * 64 + lane;
  const int row0   = eidx0 >> 2;
  const int col0   = (eidx0 & 3) * 8;
  const int chunk1 = wv + 4;
  const int eidx1  = chunk1 * 64 + lane;
  const int row1   = eidx1 >> 2;
  const int col1   = (eidx1 & 3) * 8;
  const unsigned short* gA0 = A  + (size_t)(bm + row0) * K + col0;
  const unsigned short* gB0 = Bt + (size_t)(bn + row0) * K + col0;
  const unsigned short* gA1 = A  + (size_t)(bm + row1) * K + col1;
  const unsigned short* gB1 = Bt + (size_t)(bn + row1) * K + col1;

#define STAGE(buf, k0)                                                              \
  do {                                                                              \
    __builtin_amdgcn_global_load_lds(                                               \
        (const __attribute__((address_space(1))) unsigned int*)(gA0 + (k0)),        \
        (__attribute__((address_space(3))) unsigned int*)&As[buf][chunk0 * 512],    \
        16, 0, 0);                                                                  \
    __builtin_amdgcn_global_load_lds(                                               \
        (const __attribute__((address_space(1))) unsigned int*)(gB0 + (k0)),        \
        (__attribute__((address_space(3))) unsigned int*)&Bs[buf][chunk0 * 512],    \
        16, 0, 0);                                                                  \
    __builtin_amdgcn_global_load_lds(                                               \
        (const __attribute__((address_space(1))) unsigned int*)(gA1 + (k0)),        \
        (__attribute__((address_space(3))) unsigned int*)&As[buf][chunk1 * 512],    \
        16, 0, 0);                                                                  \
    __builtin_amdgcn_global_load_lds(                                               \
        (const __attribute__((address_space(1))) unsigned int*)(gB1 + (k0)),        \
        (__attribute__((address_space(3))) unsigned int*)&Bs[buf][chunk1 * 512],    \
        16, 0, 0);                                                                  \
  } while (0)

  f32x4 acc[4][4] = {};

  const int nK = K / BK;
  STAGE(0, 0);                             // prologue: tile 0 in flight
  int cur = 0;
  for (int kt = 0; kt < nK; ++kt) {
    int nxt = (cur == 2) ? 0 : cur + 1;
    if (kt + 1 < nK) {
      STAGE(nxt, (kt + 1) * BK);           // this iter's stage: stays in flight
      asm volatile("s_waitcnt vmcnt(4)" ::: "memory");   // only buf[cur] landed
    } else {
      asm volatile("s_waitcnt vmcnt(0)" ::: "memory");
    }
    __builtin_amdgcn_s_barrier();          // all waves: buf[cur] visible
    __builtin_amdgcn_sched_barrier(0);     // pin: no LDS reads above this point

    short8 af[4], bf[4];
    const int kofs = (lane >> 4) * 8;
#pragma unroll
    for (int i = 0; i < 4; ++i) {
      int ar = wr * 64 + i * 16 + (lane & 15);
      af[i] = *(const short8*)&As[cur][ar * BK + kofs];
      int br = wc * 64 + i * 16 + (lane & 15);
      bf[i] = *(const short8*)&Bs[cur][br * BK + kofs];
    }
#pragma unroll
    for (int i = 0; i < 4; ++i)
#pragma unroll
      for (int j = 0; j < 4; ++j)
        acc[i][j] = __builtin_amdgcn_mfma_f32_16x16x32_bf16(af[i], bf[j], acc[i][j], 0, 0, 0);
    cur = nxt;
  }
#undef STAGE

  // epilogue: C/D layout col = lane&15, row = (lane>>4)*4 + r
  const int colBase = bn + wc * 64;
  const int rowBase = bm + wr * 64;
#pragma unroll
  for (int i = 0; i < 4; ++i) {
#pragma unroll
    for (int j = 0; j < 4; ++j) {
      int c = colBase + j * 16 + (lane & 15);
#pragma unroll
      for (int r4 = 0; r4 < 4; ++r4) {
        int rr = rowBase + i * 16 + (lane >> 4) * 4 + r4;
        float v = acc[i][j][r4];
        if (MODE == 0) {
          C[(size_t)rr * N + c] = v;
        } else {
          if (c < nSplit) {
            float t = v + bias[c];
            C[(size_t)rr * nSplit + c] = (t > 20.f) ? t : log1pf(expf(t));
          } else if (c < nSplit + 32) {
            C2[(size_t)rr * 32 + (c - nSplit)] = v;
          }
        }
      }
    }
  }
}

// ---------------- causal depthwise conv (K=4) + SiLU, x4 channels/thread ----------------
__global__ __launch_bounds__(256) void conv_silu_k(const float* __restrict__ xz,
                                                   const float* __restrict__ cw,
                                                   const float* __restrict__ cb,
                                                   float* __restrict__ xc,
                                                   unsigned short* __restrict__ xcb) {
  int idx = blockIdx.x * 256 + threadIdx.x;          // B*L*DI/4 threads
  int i4  = idx * 4;
  int c4  = i4 & (DI - 1);                           // channel base (multiple of 4)
  int row = i4 >> 11;                                // b*L + t
  int t   = row & (LL - 1);
  size_t base = (size_t)row * 4096 + c4;
  float4 x3 = *(const float4*)&xz[base];             // tap at l (w3)
  float4 x2 = (t >= 1) ? *(const float4*)&xz[base - 4096]  : float4{0, 0, 0, 0};
  float4 x1 = (t >= 2) ? *(const float4*)&xz[base - 8192]  : float4{0, 0, 0, 0};
  float4 x0 = (t >= 3) ? *(const float4*)&xz[base - 12288] : float4{0, 0, 0, 0};
  float4 bias = *(const float4*)&cb[c4];
  float4 w[4];
#pragma unroll
  for (int j = 0; j < 4; ++j) w[j] = *(const float4*)&cw[(c4 + j) * 4];
  float vx3[4] = {x3.x, x3.y, x3.z, x3.w};
  float vx2[4] = {x2.x, x2.y, x2.z, x2.w};
  float vx1[4] = {x1.x, x1.y, x1.z, x1.w};
  float vx0[4] = {x0.x, x0.y, x0.z, x0.w};
  float vb[4]  = {bias.x, bias.y, bias.z, bias.w};
  float4 so;
  ushort4 sb;
  float res[4];
#pragma unroll
  for (int j = 0; j < 4; ++j) {
    float v = vb[j];
    v = fmaf(vx3[j], w[j].w, v);
    v = fmaf(vx2[j], w[j].z, v);
    v = fmaf(vx1[j], w[j].y, v);
    v = fmaf(vx0[j], w[j].x, v);
    res[j] = v / (1.f + expf(-v));                   // SiLU
  }
  so.x = res[0]; so.y = res[1]; so.z = res[2]; so.w = res[3];
  sb.x = f2bf(res[0]); sb.y = f2bf(res[1]); sb.z = f2bf(res[2]); sb.w = f2bf(res[3]);
  *(float4*)&xc[i4] = so;
  *(ushort4*)&xcb[i4] = sb;
}

// ---------------- parallel selective scan, pass 1 ----------------
__global__ __launch_bounds__(256) void scan1_k(const float* __restrict__ dt,
                                               const float* __restrict__ u,
                                               const float* __restrict__ BC,
                                               const float* __restrict__ A_log,
                                               float* __restrict__ Pc,
                                               float* __restrict__ Sc) {
  int tid = threadIdx.x;
  int b   = blockIdx.y;
  int cg  = blockIdx.x / NC;           // channel group of 256
  int nc  = blockIdx.x % NC;           // chunk
  int d   = cg * 256 + tid;
  float A2[DS], h[DS];
#pragma unroll
  for (int s4 = 0; s4 < DS; s4 += 4) {
    float4 av = *(const float4*)&A_log[d * DS + s4];
    A2[s4 + 0] = -expf(av.x) * 1.44269504f;
    A2[s4 + 1] = -expf(av.y) * 1.44269504f;
    A2[s4 + 2] = -expf(av.z) * 1.44269504f;
    A2[s4 + 3] = -expf(av.w) * 1.44269504f;
    h[s4] = 0.f; h[s4 + 1] = 0.f; h[s4 + 2] = 0.f; h[s4 + 3] = 0.f;
  }
  float Tsum = 0.f;
  const int t0 = nc * LC;
  const float* dtp = dt + ((size_t)b * LL + t0) * DI + d;
  const float* up  = u  + ((size_t)b * LL + t0) * DI + d;
  const float* bcp = BC + ((size_t)b * LL + t0) * 32;     // wave-uniform -> SGPR
  for (int t = 0; t < LC; ++t) {
    float dtv = dtp[(size_t)t * DI];
    float uv  = up[(size_t)t * DI];
    float dtu = dtv * uv;
    Tsum += dtv;
#pragma unroll
    for (int s = 0; s < DS; ++s) {
      float dA = exp2f(dtv * A2[s]);
      h[s] = fmaf(dA, h[s], dtu * bcp[t * 32 + s]);
    }
  }
  size_t o = (((size_t)b * NC + nc) * DI + d) * DS;
#pragma unroll
  for (int s4 = 0; s4 < DS; s4 += 4) {
    float4 pv = {exp2f(A2[s4] * Tsum), exp2f(A2[s4 + 1] * Tsum),
                 exp2f(A2[s4 + 2] * Tsum), exp2f(A2[s4 + 3] * Tsum)};
    *(float4*)&Pc[o + s4] = pv;
    float4 sv = {h[s4], h[s4 + 1], h[s4 + 2], h[s4 + 3]};
    *(float4*)&Sc[o + s4] = sv;
  }
}

// ---------------- scan pass 1.5: stitch chunk partials into entry states ----------------
__global__ __launch_bounds__(256) void scanmid_k(const float* __restrict__ Pc,
                                                 const float* __restrict__ Sc,
                                                 float* __restrict__ H0) {
  int idx = blockIdx.x * 256 + threadIdx.x;   // 0 .. BB*DI*DS-1
  int b   = idx >> 15;                        // DI*DS = 32768
  int e   = idx & (DI * DS - 1);
  size_t base = ((size_t)b * NC) * DI * DS + e;
  float h = 0.f;
#pragma unroll
  for (int j = 0; j < NC; ++j) {
    size_t o = base + (size_t)j * DI * DS;
    H0[o] = h;
    h = fmaf(Pc[o], h, Sc[o]);
  }
}

// ---------------- parallel selective scan, pass 2 (+ gate + bf16 cast) ----------------
__global__ __launch_bounds__(256) void scan2_k(const float* __restrict__ dt,
                                               const float* __restrict__ u,
                                               const float* __restrict__ BC,
                                               const float* __restrict__ xz,
                                               const float* __restrict__ A_log,
                                               const float* __restrict__ Dp,
                                               const float* __restrict__ H0,
                                               unsigned short* __restrict__ ymb) {
  int tid = threadIdx.x;
  int b   = blockIdx.y;
  int cg  = blockIdx.x / NC;
  int nc  = blockIdx.x % NC;
  int d   = cg * 256 + tid;
  float A2[DS], h[DS];
  size_t hb = (((size_t)b * NC + nc) * DI + d) * DS;
#pragma unroll
  for (int s4 = 0; s4 < DS; s4 += 4) {
    float4 av = *(const float4*)&A_log[d * DS + s4];
    A2[s4 + 0] = -expf(av.x) * 1.44269504f;
    A2[s4 + 1] = -expf(av.y) * 1.44269504f;
    A2[s4 + 2] = -expf(av.z) * 1.44269504f;
    A2[s4 + 3] = -expf(av.w) * 1.44269504f;
    float4 hv = *(const float4*)&H0[hb + s4];
    h[s4] = hv.x; h[s4 + 1] = hv.y; h[s4 + 2] = hv.z; h[s4 + 3] = hv.w;
  }
  float Dd = Dp[d];
  const int t0 = nc * LC;
  const float* dtp = dt + ((size_t)b * LL + t0) * DI + d;
  const float* up  = u  + ((size_t)b * LL + t0) * DI + d;
  const float* bcp = BC + ((size_t)b * LL + t0) * 32;     // wave-uniform -> SGPR
  const float* zp  = xz + ((size_t)b * LL + t0) * 4096 + DI + d;
  unsigned short* yp = ymb + ((size_t)b * LL + t0) * DI + d;
  for (int t = 0; t < LC; ++t) {
    float dtv = dtp[(size_t)t * DI];
    float uv  = up[(size_t)t * DI];
    float dtu = dtv * uv;
    float y   = 0.f;
#pragma unroll
    for (int s = 0; s < DS; ++s) {
      float dA = exp2f(dtv * A2[s]);
      h[s] = fmaf(dA, h[s], dtu * bcp[t * 32 + s]);
      y = fmaf(h[s], bcp[t * 32 + 16 + s], y);
    }
    float zv = zp[(size_t)t * 4096];
    y = fmaf(Dd, uv, y);
    float sz = zv / (1.f + expf(-zv));
    yp[(size_t)t * DI] = f2bf(y * sz);
  }
}

extern "C" void kernel_launch(void* const* d_in, const int* in_sizes, int n_in,
                              void* d_out, int out_size, void* d_ws, size_t ws_size,
                              hipStream_t stream) {
  const float* x      = (const float*)d_in[0];
  const float* W_in   = (const float*)d_in[1];
  const float* conv_w = (const float*)d_in[2];
  const float* conv_b = (const float*)d_in[3];
  const float* W_x    = (const float*)d_in[4];
  const float* W_dt   = (const float*)d_in[5];
  const float* b_dt   = (const float*)d_in[6];
  const float* A_log  = (const float*)d_in[7];
  const float* Dv     = (const float*)d_in[8];
  const float* W_out  = (const float*)d_in[9];
  float* out = (float*)d_out;

  // workspace carve-up (~213 MB)
  char* w = (char*)d_ws;
  float* xz  = (float*)w;            w += (size_t)MM * 4096 * 4;   // 64 MB
  float* xc  = (float*)w;            w += (size_t)MM * DI * 4;     // 32 MB
  float* dtb = (float*)w;            w += (size_t)MM * DI * 4;     // 32 MB
  float* BC  = (float*)w;            w += (size_t)MM * 32 * 4;     // 0.5 MB
  float* Pc  = (float*)w;            w += (size_t)BB * NC * DI * DS * 4;  // 8 MB
  float* Sc  = (float*)w;            w += (size_t)BB * NC * DI * DS * 4;  // 8 MB
  float* H0  = (float*)w;            w += (size_t)BB * NC * DI * DS * 4;  // 8 MB
  unsigned short* x_b   = (unsigned short*)w; w += (size_t)MM * DM * 2;    // 8 MB
  unsigned short* xc_b  = (unsigned short*)w; w += (size_t)MM * DI * 2;    // 16 MB
  unsigned short* ym_b  = (unsigned short*)w; w += (size_t)MM * DI * 2;    // 16 MB
  unsigned short* WinT  = (unsigned short*)w; w += (size_t)(2 * DI) * DM * 2;  // 8 MB
  unsigned short* WcatT = (unsigned short*)w; w += (size_t)NCAT * DI * 2;      // 8.5 MB
  unsigned short* WoutT = (unsigned short*)w; w += (size_t)DM * DI * 2;        // 4 MB

  // 1) casts + weight transposes (bf16, B^T layout for gemm_bt)
  cast_bf16_k<<<(MM * DM) / 1024, 256, 0, stream>>>(x, x_b, MM * DM);
  transpose_cast_k<<<dim3(4096 / 32, DM / 32), dim3(32, 8), 0, stream>>>(W_in, WinT, DM, 4096);
  transpose_cast_k<<<dim3(DI / 32, DI / 32), dim3(32, 8), 0, stream>>>(W_dt, WcatT, DI, DI);
  transpose_cast_k<<<dim3(1, DI / 32), dim3(32, 8), 0, stream>>>(W_x, WcatT + (size_t)DI * DI, DI, 32);
  hipMemsetAsync(WcatT + (size_t)(DI + 32) * DI, 0, (size_t)(NCAT - DI - 32) * DI * 2, stream);
  transpose_cast_k<<<dim3(DM / 32, DI / 32), dim3(32, 8), 0, stream>>>(W_out, WoutT, DI, DM);

  // 2) xz = x @ W_in   (4096 x 4096, K=1024)
  gemm_bt_k<0><<<(MM / BM) * (4096 / BN), 256, 0, stream>>>(x_b, WinT, xz, MM, 4096, DM,
                                                            nullptr, nullptr, 0);
  // 3) xc = silu(conv(xp))  -- 4 channels per thread
  conv_silu_k<<<(MM * DI) / 1024, 256, 0, stream>>>(xz, conv_w, conv_b, xc, xc_b);

  // 4) [dt | BC] = xc @ [W_dt | W_x] with softplus+bias epilogue on dt half
  gemm_bt_k<1><<<(MM / BM) * (NCAT / BN), 256, 0, stream>>>(xc_b, WcatT, dtb, MM, NCAT, DI,
                                                            b_dt, BC, DI);
  // 5) chunked parallel selective scan (reg-state) + D*u + silu(z) gate -> ym (bf16)
  scan1_k<<<dim3((DI / 256) * NC, BB), 256, 0, stream>>>(dtb, xc, BC, A_log, Pc, Sc);
  scanmid_k<<<(BB * DI * DS) / 256, 256, 0, stream>>>(Pc, Sc, H0);
  scan2_k<<<dim3((DI / 256) * NC, BB), 256, 0, stream>>>(dtb, xc, BC, xz, A_log, Dv, H0, ym_b);

  // 6) out = ym @ W_out  (4096 x 1024, K=2048)
  gemm_bt_k<0><<<(MM / BM) * (DM / BN), 256, 0, stream>>>(ym_b, WoutT, out, MM, DM, DI,
                                                          nullptr, nullptr, 0);
}